// Round 4
// baseline (465.509 us; speedup 1.0000x reference)
//
#include <hip/hip_runtime.h>
#include <math.h>

#define DIM 128

typedef __attribute__((ext_vector_type(8))) short bf16x8;
typedef __attribute__((ext_vector_type(4))) float f32x4;

__device__ __forceinline__ ushort f2bf(float f) {  // RTNE
  unsigned u = __float_as_uint(f);
  return (ushort)((u + 0x7FFFu + ((u >> 16) & 1u)) >> 16);
}
__device__ __forceinline__ float bf2f(ushort h) {
  return __uint_as_float(((unsigned)h) << 16);
}

// ---------------- K1: pure histogram + rank (atomic stream, nothing co-resident) ----------------
// R0-R2 fit: T_prep ~= T_atomic(55-58us) + streamed_bytes/6TB/s -> co-streaming is
// additive, not hidden. So the hist runs ALONE at minimum resources.
__global__ __launch_bounds__(256) void hist_kernel(const int* __restrict__ dst,
                                                   unsigned* __restrict__ deg,
                                                   unsigned* __restrict__ rank, int E) {
  int gid = blockIdx.x * 256 + threadIdx.x;
  if (gid < E) rank[gid] = atomicAdd(&deg[dst[gid]], 1u);
}

// ---------------- two-level exclusive scan over deg (+ fused dinv) ----------------
__global__ __launch_bounds__(256) void scan_block_kernel(const unsigned* __restrict__ deg,
                                                         unsigned* __restrict__ excl,
                                                         unsigned* __restrict__ partial,
                                                         float* __restrict__ dinv, int N) {
  __shared__ unsigned s[256];
  int i = blockIdx.x * 256 + threadIdx.x;
  unsigned v = (i < N) ? deg[i] : 0u;
  if (i < N) dinv[i] = 1.0f / fmaxf((float)v, 1.0f);
  s[threadIdx.x] = v;
  __syncthreads();
#pragma unroll
  for (int d = 1; d < 256; d <<= 1) {
    unsigned t = (threadIdx.x >= d) ? s[threadIdx.x - d] : 0u;
    __syncthreads();
    s[threadIdx.x] += t;
    __syncthreads();
  }
  if (i < N) excl[i] = s[threadIdx.x] - v;
  if (threadIdx.x == 255) partial[blockIdx.x] = s[255];
}

__global__ __launch_bounds__(256) void scan_partials_kernel(unsigned* __restrict__ partial, int B) {
  __shared__ unsigned s[256];
  __shared__ unsigned carry;
  if (threadIdx.x == 0) carry = 0u;
  __syncthreads();
  for (int base = 0; base < B; base += 256) {
    int i = base + threadIdx.x;
    unsigned v = (i < B) ? partial[i] : 0u;
    s[threadIdx.x] = v;
    __syncthreads();
#pragma unroll
    for (int d = 1; d < 256; d <<= 1) {
      unsigned t = (threadIdx.x >= d) ? s[threadIdx.x - d] : 0u;
      __syncthreads();
      s[threadIdx.x] += t;
      __syncthreads();
    }
    if (i < B) partial[i] = carry + s[threadIdx.x] - v;
    __syncthreads();
    if (threadIdx.x == 0) carry += s[255];
    __syncthreads();
  }
}

__global__ __launch_bounds__(256) void add_offsets_kernel(const unsigned* __restrict__ excl,
                                                          const unsigned* __restrict__ partial,
                                                          unsigned* __restrict__ off, int N, int E) {
  int i = blockIdx.x * 256 + threadIdx.x;
  if (i < N) off[i] = excl[i] + partial[i >> 8];
  if (i == N) off[N] = (unsigned)E;
}

// ---------------- K5: gemm1 (x@W1l -> xl, x@W1r -> xr) || csr_fill || wsplit(W2) ----------------
// Layer-1 linearity: mean_agg(x)@W1l == mean_agg(x@W1l). This kernel replaces BOTH the
// x->bf16 cast kernel and the layer-1 MFMA kernel (-77 MB stream, -1 launch). The
// fill scatter rides along: its latency partially hides under the GEMM's MFMA phases.
__global__ __launch_bounds__(256, 4) void gemm1_fill_kernel(
    const float* __restrict__ x,
    const float* __restrict__ W1l, const float* __restrict__ W1r,
    ushort* __restrict__ xl, ushort* __restrict__ xr,
    const int* __restrict__ src, const int* __restrict__ dst,
    const unsigned* __restrict__ rank, const unsigned* __restrict__ off,
    int* __restrict__ csr_src, int E,
    const float* __restrict__ W2l, const float* __restrict__ W2r,
    ushort* __restrict__ tabs, int F, int G1, int N) {
  __shared__ ushort As[128 * 32];  // 8 KB: x tile, bf16, swizzled
  __shared__ ushort Bs[128 * 32];  // 8 KB: W column-tile, bf16, transposed+swizzled
  const int tid = threadIdx.x;
  const int bid = blockIdx.x;
  const int r5 = bid % 5;
  const int q5 = bid / 5;

  if (r5 != 4) {  // csr_fill role (4/5 of blocks)
    int hid = q5 * 4 + r5;
    if (hid < F) {
      int e = hid * 256 + tid;
      if (e < E) csr_src[off[dst[e]] + rank[e]] = src[e];
    }
    return;
  }
  int aid = q5;
  const int GEMMB = 2 * G1;
  if (aid >= GEMMB) {  // wsplit role: transpose+cast W2l/W2r to bf16 tabs
    int aid2 = aid - GEMMB;
    if (aid2 < 128) {
      int m = aid2 >> 6;
      const float* W = m ? W2r : W2l;
      ushort* Ht = tabs + (size_t)m * 16384;
      int idx = (aid2 & 63) * 256 + tid;
      int k = idx >> 7, n = idx & 127;
      Ht[n * DIM + k] = f2bf(W[idx]);
    }
    return;
  }

  // ---- GEMM role: out[bm:bm+128][0:128] = x @ W (fp32 in, bf16 out), x read ONCE ----
  const int m = aid / G1;  // 0: W1l -> xl, 1: W1r -> xr
  const int tile = aid % G1;
  const int bm = tile * 128;
  const float* W = m ? W1r : W1l;
  ushort* out = m ? xr : xl;

  const int wave = tid >> 6;
  const int lane = tid & 63;
  const int l15 = lane & 15;
  const int quad = lane >> 4;

  f32x4 acc[2][8];
#pragma unroll
  for (int i = 0; i < 2; ++i)
#pragma unroll
    for (int j = 0; j < 8; ++j) acc[i][j] = (f32x4){0.f, 0.f, 0.f, 0.f};

  for (int g = 0; g < 4; ++g) {
    const int kt = g << 5;
    __syncthreads();
    // stage A: x[bm..bm+127][kt..kt+31] fp32 -> bf16 swizzled (proven in R2)
#pragma unroll
    for (int c = 0; c < 4; ++c) {
      int flat = c * 256 + tid;  // float4 units, 0..1023
      int row = flat >> 3;       // 0..127
      int q4 = flat & 7;         // k = q4*4
      int grow = bm + row;
      if (grow >= N) grow = N - 1;
      float4 v = *(const float4*)(x + (size_t)grow * DIM + kt + q4 * 4);
      int kb = q4 >> 1, ki = (q4 & 1) << 2;
      uint2 pk;
      pk.x = (unsigned)f2bf(v.x) | ((unsigned)f2bf(v.y) << 16);
      pk.y = (unsigned)f2bf(v.z) | ((unsigned)f2bf(v.w) << 16);
      *(uint2*)(&As[row * 32 + ((kb ^ (row & 3)) << 3) + ki]) = pk;
    }
    // stage B: W[kt..kt+31][0..127] fp32 -> Bs[n][k] bf16 (transpose in store)
#pragma unroll
    for (int c = 0; c < 16; ++c) {
      int idx = c * 256 + tid;  // 0..4095
      int kk = idx >> 7;        // 0..31
      int n = idx & 127;
      Bs[n * 32 + (((kk >> 3) ^ (n & 3)) << 3) + (kk & 7)] =
          f2bf(W[(size_t)(kt + kk) * DIM + n]);
    }
    __syncthreads();
    bf16x8 af[2];
#pragma unroll
    for (int i = 0; i < 2; ++i) {
      int ar = (wave << 5) + (i << 4) + l15;
      af[i] = *(const bf16x8*)(&As[ar * 32 + ((quad ^ (ar & 3)) << 3)]);
    }
#pragma unroll
    for (int j = 0; j < 8; ++j) {
      int br = (j << 4) + l15;
      bf16x8 bfr = *(const bf16x8*)(&Bs[br * 32 + ((quad ^ (br & 3)) << 3)]);
#pragma unroll
      for (int i = 0; i < 2; ++i)
        acc[i][j] = __builtin_amdgcn_mfma_f32_16x16x32_bf16(af[i], bfr, acc[i][j], 0, 0, 0);
    }
  }

  // epilogue: raw bf16 store (no bias, no relu)
#pragma unroll
  for (int i = 0; i < 2; ++i) {
#pragma unroll
    for (int r = 0; r < 4; ++r) {
      const int grow = bm + (wave << 5) + (i << 4) + (quad << 2) + r;
      if (grow < N) {
#pragma unroll
        for (int j = 0; j < 8; ++j)
          out[(size_t)grow * DIM + (j << 4) + l15] = f2bf(acc[i][j][r]);
      }
    }
  }
}

// ---------------- gather body macro: wave-per-node aggregation into acc[8] ----------------
#define GATHER_BODY(TABLE)                                                       \
  const int node = (blockIdx.x * 256 + threadIdx.x) >> 6;                        \
  if (node >= N) return;                                                         \
  const int lane = threadIdx.x & 63;                                             \
  const int eslot = lane >> 4;                                                   \
  const int col = lane & 15;                                                     \
  const unsigned beg = off[node], end = off[node + 1];                           \
  const ushort* fbase = (TABLE) + col * 8;                                       \
  float acc[8];                                                                  \
  _Pragma("unroll") for (int t = 0; t < 8; ++t) acc[t] = 0.f;                    \
  auto accum = [&](int4 v) {                                                     \
    unsigned w0 = (unsigned)v.x, w1 = (unsigned)v.y;                             \
    unsigned w2 = (unsigned)v.z, w3 = (unsigned)v.w;                             \
    acc[0] += __uint_as_float(w0 << 16);                                         \
    acc[1] += __uint_as_float(w0 & 0xFFFF0000u);                                 \
    acc[2] += __uint_as_float(w1 << 16);                                         \
    acc[3] += __uint_as_float(w1 & 0xFFFF0000u);                                 \
    acc[4] += __uint_as_float(w2 << 16);                                         \
    acc[5] += __uint_as_float(w2 & 0xFFFF0000u);                                 \
    acc[6] += __uint_as_float(w3 << 16);                                         \
    acc[7] += __uint_as_float(w3 & 0xFFFF0000u);                                 \
  };                                                                             \
  unsigned base = beg;                                                           \
  for (; base + 16 <= end; base += 16) {                                         \
    int s0 = csr_src[base + eslot];                                              \
    int s1 = csr_src[base + 4 + eslot];                                          \
    int s2 = csr_src[base + 8 + eslot];                                          \
    int s3 = csr_src[base + 12 + eslot];                                         \
    int4 v0 = *(const int4*)(fbase + (size_t)s0 * DIM);                          \
    int4 v1 = *(const int4*)(fbase + (size_t)s1 * DIM);                          \
    int4 v2 = *(const int4*)(fbase + (size_t)s2 * DIM);                          \
    int4 v3 = *(const int4*)(fbase + (size_t)s3 * DIM);                          \
    accum(v0); accum(v1); accum(v2); accum(v3);                                  \
  }                                                                              \
  for (; base + 8 <= end; base += 8) {                                           \
    int s0 = csr_src[base + eslot];                                              \
    int s1 = csr_src[base + 4 + eslot];                                          \
    int4 v0 = *(const int4*)(fbase + (size_t)s0 * DIM);                          \
    int4 v1 = *(const int4*)(fbase + (size_t)s1 * DIM);                          \
    accum(v0); accum(v1);                                                        \
  }                                                                              \
  for (unsigned e = base + eslot; e < end; e += 4) {                             \
    int s = csr_src[e];                                                          \
    int4 v = *(const int4*)(fbase + (size_t)s * DIM);                            \
    accum(v);                                                                    \
  }                                                                              \
  _Pragma("unroll") for (int t = 0; t < 8; ++t) {                                \
    acc[t] += __shfl_xor(acc[t], 32, 64);                                        \
    acc[t] += __shfl_xor(acc[t], 16, 64);                                        \
  }

// ---------------- gather1: agg(xl), fused layer-1 epilogue -> h1 (proven in R2) ----------------
__global__ __launch_bounds__(256) void gather1_kernel(
    const ushort* __restrict__ xl, const int* __restrict__ csr_src,
    const unsigned* __restrict__ off, const float* __restrict__ dinv,
    const ushort* __restrict__ xr, const float* __restrict__ b1,
    ushort* __restrict__ h1, int N) {
  GATHER_BODY(xl)
  if (eslot == 0) {
    float di = dinv[node];
    int4 xv = *(const int4*)(xr + (size_t)node * DIM + col * 8);
    float4 ba = *(const float4*)(b1 + col * 8);
    float4 bb = *(const float4*)(b1 + col * 8 + 4);
    unsigned w0 = (unsigned)xv.x, w1 = (unsigned)xv.y;
    unsigned w2 = (unsigned)xv.z, w3 = (unsigned)xv.w;
    float h[8];
    h[0] = fmaxf(acc[0] * di + __uint_as_float(w0 << 16) + ba.x, 0.f);
    h[1] = fmaxf(acc[1] * di + __uint_as_float(w0 & 0xFFFF0000u) + ba.y, 0.f);
    h[2] = fmaxf(acc[2] * di + __uint_as_float(w1 << 16) + ba.z, 0.f);
    h[3] = fmaxf(acc[3] * di + __uint_as_float(w1 & 0xFFFF0000u) + ba.w, 0.f);
    h[4] = fmaxf(acc[4] * di + __uint_as_float(w2 << 16) + bb.x, 0.f);
    h[5] = fmaxf(acc[5] * di + __uint_as_float(w2 & 0xFFFF0000u) + bb.y, 0.f);
    h[6] = fmaxf(acc[6] * di + __uint_as_float(w3 << 16) + bb.z, 0.f);
    h[7] = fmaxf(acc[7] * di + __uint_as_float(w3 & 0xFFFF0000u) + bb.w, 0.f);
    unsigned ph[4];
#pragma unroll
    for (int t = 0; t < 4; ++t)
      ph[t] = (unsigned)f2bf(h[2 * t]) | ((unsigned)f2bf(h[2 * t + 1]) << 16);
    *(int4*)(h1 + (size_t)node * DIM + col * 8) =
        make_int4((int)ph[0], (int)ph[1], (int)ph[2], (int)ph[3]);
  }
}

// ---------------- gather2: agg(h1) * dinv -> aggH bf16 (R0 structure, proven) ----------------
__global__ __launch_bounds__(256) void gather_wave_kernel(
    const ushort* __restrict__ featH, const int* __restrict__ csr_src,
    const unsigned* __restrict__ off, const float* __restrict__ dinv,
    ushort* __restrict__ aggH, int N) {
  GATHER_BODY(featH)
  if (eslot == 0) {
    float di = dinv[node];
    unsigned ph[4];
#pragma unroll
    for (int t = 0; t < 4; ++t) {
      ph[t] = (unsigned)f2bf(acc[2 * t] * di) | ((unsigned)f2bf(acc[2 * t + 1] * di) << 16);
    }
    *(int4*)(aggH + (size_t)node * DIM + col * 8) =
        make_int4((int)ph[0], (int)ph[1], (int)ph[2], (int)ph[3]);
  }
}

// ---------------- MFMA SAGE layer (R0's proven kernel, used for layer 2 + fused lin3) ----------------
__global__ __launch_bounds__(256) void sage_mfma_kernel(
    const ushort* __restrict__ aggH, const ushort* xH,
    const ushort* __restrict__ WlH, const ushort* __restrict__ WrH,
    const float* __restrict__ bias,
    const float* __restrict__ W3l, const float* __restrict__ W3r,
    ushort* __restrict__ outH, float* __restrict__ y, int N) {
  __shared__ ushort As[128 * 64];  // 16 KB
  __shared__ ushort Bs[128 * 64];  // 16 KB

  const int tid = threadIdx.x;
  const int bm = blockIdx.x * 128;
  const int wave = tid >> 6;
  const int lane = tid & 63;
  const int l15 = lane & 15;
  const int quad = lane >> 4;
  const int wm = wave >> 1;
  const int wn = wave & 1;

  f32x4 acc[4][4];
#pragma unroll
  for (int i = 0; i < 4; ++i)
#pragma unroll
    for (int j = 0; j < 4; ++j) acc[i][j] = (f32x4){0.f, 0.f, 0.f, 0.f};

  for (int g = 0; g < 4; ++g) {
    const ushort* Ap = (g < 2) ? aggH : xH;
    const ushort* Wp = (g < 2) ? WlH : WrH;
    const int kt = (g & 1) << 6;
    __syncthreads();
#pragma unroll
    for (int c = 0; c < 4; ++c) {
      int flat = c * 256 + tid;
      int row = flat >> 3;
      int kg = flat & 7;
      int swz = (kg ^ (row & 7)) << 3;
      int grow = bm + row;
      if (grow >= N) grow = N - 1;
      *(int4*)(&As[row * 64 + swz]) = *(const int4*)(Ap + (size_t)grow * DIM + kt + kg * 8);
      *(int4*)(&Bs[row * 64 + swz]) = *(const int4*)(Wp + (size_t)row * DIM + kt + kg * 8);
    }
    __syncthreads();
#pragma unroll
    for (int ks = 0; ks < 2; ++ks) {
      bf16x8 af[4], bfr[4];
      int kg = (ks << 2) + quad;
#pragma unroll
      for (int i = 0; i < 4; ++i) {
        int ar = (wm << 6) + (i << 4) + l15;
        af[i] = *(const bf16x8*)(&As[ar * 64 + ((kg ^ (ar & 7)) << 3)]);
        int br = (wn << 6) + (i << 4) + l15;
        bfr[i] = *(const bf16x8*)(&Bs[br * 64 + ((kg ^ (br & 7)) << 3)]);
      }
#pragma unroll
      for (int i = 0; i < 4; ++i)
#pragma unroll
        for (int j = 0; j < 4; ++j)
          acc[i][j] = __builtin_amdgcn_mfma_f32_16x16x32_bf16(af[i], bfr[j], acc[i][j], 0, 0, 0);
    }
  }

  __syncthreads();  // As/Bs dead; alias epilogue buffers onto As
  float* WcF = reinterpret_cast<float*>(As);        // [128][4] = 2 KB
  float* YpF = reinterpret_cast<float*>(As) + 512;  // [128][4][2] = 4 KB

  if (W3l) {
    for (int t = tid; t < 512; t += 256) {
      int col = t >> 2, c = t & 3;
      WcF[t] = (c < 2) ? W3l[col * 2 + c] : W3r[col * 2 + (c - 2)];
    }
    __syncthreads();
  }

  float bv[4];
#pragma unroll
  for (int j = 0; j < 4; ++j) bv[j] = bias[(wn << 6) + (j << 4) + l15];

#pragma unroll
  for (int i = 0; i < 4; ++i) {
#pragma unroll
    for (int r = 0; r < 4; ++r) {
      const int rowl = (wm << 6) + (i << 4) + (quad << 2) + r;
      const int grow = bm + rowl;
      float p0 = 0.f, p1 = 0.f, p2 = 0.f, p3 = 0.f;
#pragma unroll
      for (int j = 0; j < 4; ++j) {
        int col = (wn << 6) + (j << 4) + l15;
        float v = fmaxf(acc[i][j][r] + bv[j], 0.f);
        ushort h = f2bf(v);
        if (outH && grow < N) outH[(size_t)grow * DIM + col] = h;
        if (W3l) {
          float qv = bf2f(h);
          p0 += qv * WcF[col * 4 + 0];
          p1 += qv * WcF[col * 4 + 1];
          p2 += qv * WcF[col * 4 + 2];
          p3 += qv * WcF[col * 4 + 3];
        }
      }
      if (W3l) {
#pragma unroll
        for (int o = 1; o < 16; o <<= 1) {
          p0 += __shfl_xor(p0, o, 64);
          p1 += __shfl_xor(p1, o, 64);
          p2 += __shfl_xor(p2, o, 64);
          p3 += __shfl_xor(p3, o, 64);
        }
        if (l15 == 0) {
          YpF[(rowl * 4 + 0) * 2 + wn] = p0;
          YpF[(rowl * 4 + 1) * 2 + wn] = p1;
          YpF[(rowl * 4 + 2) * 2 + wn] = p2;
          YpF[(rowl * 4 + 3) * 2 + wn] = p3;
        }
      }
    }
  }

  if (W3l) {
    __syncthreads();
    for (int t = tid; t < 512; t += 256) {
      int grow = bm + (t >> 2);
      if (grow < N) y[(size_t)grow * 4 + (t & 3)] = YpF[t * 2 + 0] + YpF[t * 2 + 1];
    }
  }
}

// ---------------- layer 3: 2-dim CSR gather + bias + relu + log_softmax ----------------
__global__ __launch_bounds__(256) void final3_kernel(const float* __restrict__ y,
                                                     const int* __restrict__ csr_src,
                                                     const unsigned* __restrict__ off,
                                                     const float* __restrict__ dinv,
                                                     const float* __restrict__ b3,
                                                     float* __restrict__ out, int N) {
  int n = blockIdx.x * 256 + threadIdx.x;
  if (n >= N) return;
  unsigned beg = off[n], end = off[n + 1];
  float s0 = 0.f, s1 = 0.f;
  for (unsigned e = beg; e < end; ++e) {
    int s = csr_src[e];
    float2 v = *reinterpret_cast<const float2*>(&y[(size_t)s * 4]);
    s0 += v.x; s1 += v.y;
  }
  float di = dinv[n];
  float o0 = fmaxf(s0 * di + y[(size_t)n * 4 + 2] + b3[0], 0.f);
  float o1 = fmaxf(s1 * di + y[(size_t)n * 4 + 3] + b3[1], 0.f);
  float m = fmaxf(o0, o1);
  float l = m + logf(expf(o0 - m) + expf(o1 - m));
  out[n * 2 + 0] = o0 - l;
  out[n * 2 + 1] = o1 - l;
}

extern "C" void kernel_launch(void* const* d_in, const int* in_sizes, int n_in,
                              void* d_out, int out_size, void* d_ws, size_t ws_size,
                              hipStream_t stream) {
  const float* x   = (const float*)d_in[0];
  const int*   ei  = (const int*)d_in[1];
  const float* W1l = (const float*)d_in[2];
  const float* W1r = (const float*)d_in[3];
  const float* b1  = (const float*)d_in[4];
  const float* W2l = (const float*)d_in[5];
  const float* W2r = (const float*)d_in[6];
  const float* b2  = (const float*)d_in[7];
  const float* W3l = (const float*)d_in[8];
  const float* W3r = (const float*)d_in[9];
  const float* b3  = (const float*)d_in[10];

  const int N = in_sizes[0] / DIM;  // 100000
  const int E = in_sizes[1] / 2;    // 1600000
  const int* src = ei;
  const int* dst = ei + E;
  const int B = (N + 255) / 256;

  char* ws = (char*)d_ws;
  size_t off_b = 0;
  auto alloc = [&](size_t bytes) {
    void* p = ws + off_b;
    off_b = (off_b + bytes + 255) & ~(size_t)255;
    return p;
  };
  unsigned* deg     = (unsigned*)alloc((size_t)N * 4);
  unsigned* excl    = (unsigned*)alloc((size_t)N * 4);
  unsigned* partial = (unsigned*)alloc((size_t)B * 4);
  unsigned* offs    = (unsigned*)alloc((size_t)(N + 1) * 4);
  unsigned* rank    = (unsigned*)alloc((size_t)E * 4);
  int*      csr_src = (int*)alloc((size_t)E * 4);
  float*    dinv    = (float*)alloc((size_t)N * 4);
  ushort*   xl      = (ushort*)alloc((size_t)N * DIM * 2);
  ushort*   xr      = (ushort*)alloc((size_t)N * DIM * 2);
  ushort*   h1      = (ushort*)alloc((size_t)N * DIM * 2);
  ushort*   tabs    = (ushort*)alloc((size_t)2 * 16384 * 2);
  float*    y       = (float*)alloc((size_t)N * 4 * 4);
  // aggH aliases xl: xl is last read by gather1; aggH is written by gather_wave
  // strictly afterwards. Keeps workspace at R2's proven ~93 MB (R3's extra 25.6 MB
  // standalone aggH likely overflowed ws -> container crash).
  ushort* aggH = xl;

  const int F  = (E + 255) / 256;   // 6250 fill tiles
  const int G1 = (N + 127) / 128;   // 782 row tiles
  const int GEMMB = 2 * G1;         // 1564 gemm blocks
  const int AUXN = GEMMB + 128;     // + wsplit
  const int FQ = (F + 3) / 4;       // 1563
  const int P = (AUXN > FQ) ? AUXN : FQ;

  hipMemsetAsync(deg, 0, (size_t)N * 4, stream);
  // K1: pure atomic histogram (no co-resident streaming)
  hist_kernel<<<F, 256, 0, stream>>>(dst, deg, rank, E);
  // scan chain
  scan_block_kernel<<<B, 256, 0, stream>>>(deg, excl, partial, dinv, N);
  scan_partials_kernel<<<1, 256, 0, stream>>>(partial, B);
  add_offsets_kernel<<<(N + 256) / 256, 256, 0, stream>>>(excl, partial, offs, N, E);
  // K5: layer-1 GEMMs (linearity) || csr_fill || W2 wsplit
  gemm1_fill_kernel<<<5 * P, 256, 0, stream>>>(x, W1l, W1r, xl, xr,
                                               src, dst, rank, offs, csr_src, E,
                                               W2l, W2r, tabs, F, G1, N);

  const ushort* W2lH = tabs;
  const ushort* W2rH = tabs + 16384;
  const int G = (N + 127) / 128;
  const int gather_grid = (N + 3) / 4;  // one wave per node

  // layer 1: h1 = relu(mean_agg(xl) + xr + b1)  (fused epilogue, no MFMA kernel)
  gather1_kernel<<<gather_grid, 256, 0, stream>>>(xl, csr_src, offs, dinv, xr, b1, h1, N);
  // layer 2 (R0 structure): agg2 = mean_agg(h1); y = lin3(relu(agg2@W2l + h1@W2r + b2))
  gather_wave_kernel<<<gather_grid, 256, 0, stream>>>(h1, csr_src, offs, dinv, aggH, N);
  sage_mfma_kernel<<<G, 256, 0, stream>>>(aggH, h1, W2lH, W2rH, b2,
                                          W3l, W3r, nullptr, y, N);
  // layer 3
  final3_kernel<<<(N + 255) / 256, 256, 0, stream>>>(y, csr_src, offs, dinv, b3, (float*)d_out, N);
}

// Round 5
// 447.885 us; speedup vs baseline: 1.0393x; 1.0393x over previous
//
#include <hip/hip_runtime.h>
#include <math.h>

#define DIM 128

typedef __attribute__((ext_vector_type(8))) short bf16x8;
typedef __attribute__((ext_vector_type(4))) float f32x4;

__device__ __forceinline__ ushort f2bf(float f) {  // RTNE
  unsigned u = __float_as_uint(f);
  return (ushort)((u + 0x7FFFu + ((u >> 16) & 1u)) >> 16);
}
__device__ __forceinline__ float bf2f(ushort h) {
  return __uint_as_float(((unsigned)h) << 16);
}

// ---------------- K1: pure histogram + rank. Atomic-latency-bound (~22 atomics/ns
// device ceiling); R0-R4 showed ANY co-resident memory role is additive, so it runs
// alone at minimal resources (8 VGPR, no LDS -> max occupancy). ----------------
__global__ __launch_bounds__(256) void hist_kernel(const int* __restrict__ dst,
                                                   unsigned* __restrict__ deg,
                                                   unsigned* __restrict__ rank, int E) {
  int gid = blockIdx.x * 256 + threadIdx.x;
  if (gid < E) rank[gid] = atomicAdd(&deg[dst[gid]], 1u);
}

// ---------------- two-level exclusive scan over deg (+ fused dinv) ----------------
__global__ __launch_bounds__(256) void scan_block_kernel(const unsigned* __restrict__ deg,
                                                         unsigned* __restrict__ excl,
                                                         unsigned* __restrict__ partial,
                                                         float* __restrict__ dinv, int N) {
  __shared__ unsigned s[256];
  int i = blockIdx.x * 256 + threadIdx.x;
  unsigned v = (i < N) ? deg[i] : 0u;
  if (i < N) dinv[i] = 1.0f / fmaxf((float)v, 1.0f);
  s[threadIdx.x] = v;
  __syncthreads();
#pragma unroll
  for (int d = 1; d < 256; d <<= 1) {
    unsigned t = (threadIdx.x >= d) ? s[threadIdx.x - d] : 0u;
    __syncthreads();
    s[threadIdx.x] += t;
    __syncthreads();
  }
  if (i < N) excl[i] = s[threadIdx.x] - v;
  if (threadIdx.x == 255) partial[blockIdx.x] = s[255];
}

__global__ __launch_bounds__(256) void scan_partials_kernel(unsigned* __restrict__ partial, int B) {
  __shared__ unsigned s[256];
  __shared__ unsigned carry;
  if (threadIdx.x == 0) carry = 0u;
  __syncthreads();
  for (int base = 0; base < B; base += 256) {
    int i = base + threadIdx.x;
    unsigned v = (i < B) ? partial[i] : 0u;
    s[threadIdx.x] = v;
    __syncthreads();
#pragma unroll
    for (int d = 1; d < 256; d <<= 1) {
      unsigned t = (threadIdx.x >= d) ? s[threadIdx.x - d] : 0u;
      __syncthreads();
      s[threadIdx.x] += t;
      __syncthreads();
    }
    if (i < B) partial[i] = carry + s[threadIdx.x] - v;
    __syncthreads();
    if (threadIdx.x == 0) carry += s[255];
    __syncthreads();
  }
}

__global__ __launch_bounds__(256) void add_offsets_kernel(const unsigned* __restrict__ excl,
                                                          const unsigned* __restrict__ partial,
                                                          unsigned* __restrict__ off, int N, int E) {
  int i = blockIdx.x * 256 + threadIdx.x;
  if (i < N) off[i] = excl[i] + partial[i >> 8];
  if (i == N) off[N] = (unsigned)E;
}

// ---------------- CSR fill: atomic-free scatter, alone (R4: fusing it with GEMM was
// additive +interference; its write-allocate traffic ~100 MB is irreducible here) ----------------
__global__ __launch_bounds__(256) void csr_fill_kernel(const int* __restrict__ src,
                                                       const int* __restrict__ dst,
                                                       const unsigned* __restrict__ rank,
                                                       const unsigned* __restrict__ off,
                                                       int* __restrict__ csr_src, int E) {
  int e = blockIdx.x * 256 + threadIdx.x;
  if (e >= E) return;
  csr_src[off[dst[e]] + rank[e]] = src[e];
}

// ---------------- gemm1 + wsplit: xl = x@W1l, xr = x@W1r (fp32 in, bf16 out) ----------------
// Layer-1 linearity: mean_agg(x)@W1l == mean_agg(x@W1l). Replaces the x->bf16 cast
// kernel AND the layer-1 MFMA kernel (which streamed 77 MB). GEMM role proven in R4.
__global__ __launch_bounds__(256, 4) void gemm1_wsplit_kernel(
    const float* __restrict__ x,
    const float* __restrict__ W1l, const float* __restrict__ W1r,
    ushort* __restrict__ xl, ushort* __restrict__ xr,
    const float* __restrict__ W2l, const float* __restrict__ W2r,
    ushort* __restrict__ tabs, int G1, int N) {
  __shared__ ushort As[128 * 32];  // 8 KB: x tile, bf16, swizzled
  __shared__ ushort Bs[128 * 32];  // 8 KB: W column-tile, bf16, transposed+swizzled
  const int tid = threadIdx.x;
  int aid = blockIdx.x;
  const int GEMMB = 2 * G1;
  if (aid >= GEMMB) {  // wsplit role: transpose+cast W2l/W2r to bf16 tabs (tiny tail)
    int aid2 = aid - GEMMB;
    if (aid2 < 128) {
      int m = aid2 >> 6;
      const float* W = m ? W2r : W2l;
      ushort* Ht = tabs + (size_t)m * 16384;
      int idx = (aid2 & 63) * 256 + tid;
      int k = idx >> 7, n = idx & 127;
      Ht[n * DIM + k] = f2bf(W[idx]);
    }
    return;
  }

  // ---- GEMM role: out[bm:bm+128][0:128] = x @ W, x tile read ONCE for 128 cols ----
  const int m = aid / G1;  // 0: W1l -> xl, 1: W1r -> xr
  const int tile = aid % G1;
  const int bm = tile * 128;
  const float* W = m ? W1r : W1l;
  ushort* out = m ? xr : xl;

  const int wave = tid >> 6;
  const int lane = tid & 63;
  const int l15 = lane & 15;
  const int quad = lane >> 4;

  f32x4 acc[2][8];
#pragma unroll
  for (int i = 0; i < 2; ++i)
#pragma unroll
    for (int j = 0; j < 8; ++j) acc[i][j] = (f32x4){0.f, 0.f, 0.f, 0.f};

  for (int g = 0; g < 4; ++g) {
    const int kt = g << 5;
    __syncthreads();
    // stage A: x[bm..bm+127][kt..kt+31] fp32 -> bf16 swizzled
#pragma unroll
    for (int c = 0; c < 4; ++c) {
      int flat = c * 256 + tid;  // float4 units, 0..1023
      int row = flat >> 3;       // 0..127
      int q4 = flat & 7;         // k = q4*4
      int grow = bm + row;
      if (grow >= N) grow = N - 1;
      float4 v = *(const float4*)(x + (size_t)grow * DIM + kt + q4 * 4);
      int kb = q4 >> 1, ki = (q4 & 1) << 2;
      uint2 pk;
      pk.x = (unsigned)f2bf(v.x) | ((unsigned)f2bf(v.y) << 16);
      pk.y = (unsigned)f2bf(v.z) | ((unsigned)f2bf(v.w) << 16);
      *(uint2*)(&As[row * 32 + ((kb ^ (row & 3)) << 3) + ki]) = pk;
    }
    // stage B: W[kt..kt+31][0..127] fp32 -> Bs[n][k] bf16 (transpose in store)
#pragma unroll
    for (int c = 0; c < 16; ++c) {
      int idx = c * 256 + tid;  // 0..4095
      int kk = idx >> 7;        // 0..31
      int n = idx & 127;
      Bs[n * 32 + (((kk >> 3) ^ (n & 3)) << 3) + (kk & 7)] =
          f2bf(W[(size_t)(kt + kk) * DIM + n]);
    }
    __syncthreads();
    bf16x8 af[2];
#pragma unroll
    for (int i = 0; i < 2; ++i) {
      int ar = (wave << 5) + (i << 4) + l15;
      af[i] = *(const bf16x8*)(&As[ar * 32 + ((quad ^ (ar & 3)) << 3)]);
    }
#pragma unroll
    for (int j = 0; j < 8; ++j) {
      int br = (j << 4) + l15;
      bf16x8 bfr = *(const bf16x8*)(&Bs[br * 32 + ((quad ^ (br & 3)) << 3)]);
#pragma unroll
      for (int i = 0; i < 2; ++i)
        acc[i][j] = __builtin_amdgcn_mfma_f32_16x16x32_bf16(af[i], bfr, acc[i][j], 0, 0, 0);
    }
  }

  // epilogue: raw bf16 store (no bias, no relu)
#pragma unroll
  for (int i = 0; i < 2; ++i) {
#pragma unroll
    for (int r = 0; r < 4; ++r) {
      const int grow = bm + (wave << 5) + (i << 4) + (quad << 2) + r;
      if (grow < N) {
#pragma unroll
        for (int j = 0; j < 8; ++j)
          out[(size_t)grow * DIM + (j << 4) + l15] = f2bf(acc[i][j][r]);
      }
    }
  }
}

// ---------------- gather body macro: wave-per-node aggregation into acc[8] ----------------
#define GATHER_BODY(TABLE)                                                       \
  const int node = (blockIdx.x * 256 + threadIdx.x) >> 6;                        \
  if (node >= N) return;                                                         \
  const int lane = threadIdx.x & 63;                                             \
  const int eslot = lane >> 4;                                                   \
  const int col = lane & 15;                                                     \
  const unsigned beg = off[node], end = off[node + 1];                           \
  const ushort* fbase = (TABLE) + col * 8;                                       \
  float acc[8];                                                                  \
  _Pragma("unroll") for (int t = 0; t < 8; ++t) acc[t] = 0.f;                    \
  auto accum = [&](int4 v) {                                                     \
    unsigned w0 = (unsigned)v.x, w1 = (unsigned)v.y;                             \
    unsigned w2 = (unsigned)v.z, w3 = (unsigned)v.w;                             \
    acc[0] += __uint_as_float(w0 << 16);                                         \
    acc[1] += __uint_as_float(w0 & 0xFFFF0000u);                                 \
    acc[2] += __uint_as_float(w1 << 16);                                         \
    acc[3] += __uint_as_float(w1 & 0xFFFF0000u);                                 \
    acc[4] += __uint_as_float(w2 << 16);                                         \
    acc[5] += __uint_as_float(w2 & 0xFFFF0000u);                                 \
    acc[6] += __uint_as_float(w3 << 16);                                         \
    acc[7] += __uint_as_float(w3 & 0xFFFF0000u);                                 \
  };                                                                             \
  unsigned base = beg;                                                           \
  for (; base + 16 <= end; base += 16) {                                         \
    int s0 = csr_src[base + eslot];                                              \
    int s1 = csr_src[base + 4 + eslot];                                          \
    int s2 = csr_src[base + 8 + eslot];                                          \
    int s3 = csr_src[base + 12 + eslot];                                         \
    int4 v0 = *(const int4*)(fbase + (size_t)s0 * DIM);                          \
    int4 v1 = *(const int4*)(fbase + (size_t)s1 * DIM);                          \
    int4 v2 = *(const int4*)(fbase + (size_t)s2 * DIM);                          \
    int4 v3 = *(const int4*)(fbase + (size_t)s3 * DIM);                          \
    accum(v0); accum(v1); accum(v2); accum(v3);                                  \
  }                                                                              \
  for (; base + 8 <= end; base += 8) {                                           \
    int s0 = csr_src[base + eslot];                                              \
    int s1 = csr_src[base + 4 + eslot];                                          \
    int4 v0 = *(const int4*)(fbase + (size_t)s0 * DIM);                          \
    int4 v1 = *(const int4*)(fbase + (size_t)s1 * DIM);                          \
    accum(v0); accum(v1);                                                        \
  }                                                                              \
  for (unsigned e = base + eslot; e < end; e += 4) {                             \
    int s = csr_src[e];                                                          \
    int4 v = *(const int4*)(fbase + (size_t)s * DIM);                            \
    accum(v);                                                                    \
  }                                                                              \
  _Pragma("unroll") for (int t = 0; t < 8; ++t) {                                \
    acc[t] += __shfl_xor(acc[t], 32, 64);                                        \
    acc[t] += __shfl_xor(acc[t], 16, 64);                                        \
  }

// ---------------- gather1: agg(xl), fused layer-1 epilogue -> h1 (proven R2/R4) ----------------
__global__ __launch_bounds__(256) void gather1_kernel(
    const ushort* __restrict__ xl, const int* __restrict__ csr_src,
    const unsigned* __restrict__ off, const float* __restrict__ dinv,
    const ushort* __restrict__ xr, const float* __restrict__ b1,
    ushort* __restrict__ h1, int N) {
  GATHER_BODY(xl)
  if (eslot == 0) {
    float di = dinv[node];
    int4 xv = *(const int4*)(xr + (size_t)node * DIM + col * 8);
    float4 ba = *(const float4*)(b1 + col * 8);
    float4 bb = *(const float4*)(b1 + col * 8 + 4);
    unsigned w0 = (unsigned)xv.x, w1 = (unsigned)xv.y;
    unsigned w2 = (unsigned)xv.z, w3 = (unsigned)xv.w;
    float h[8];
    h[0] = fmaxf(acc[0] * di + __uint_as_float(w0 << 16) + ba.x, 0.f);
    h[1] = fmaxf(acc[1] * di + __uint_as_float(w0 & 0xFFFF0000u) + ba.y, 0.f);
    h[2] = fmaxf(acc[2] * di + __uint_as_float(w1 << 16) + ba.z, 0.f);
    h[3] = fmaxf(acc[3] * di + __uint_as_float(w1 & 0xFFFF0000u) + ba.w, 0.f);
    h[4] = fmaxf(acc[4] * di + __uint_as_float(w2 << 16) + bb.x, 0.f);
    h[5] = fmaxf(acc[5] * di + __uint_as_float(w2 & 0xFFFF0000u) + bb.y, 0.f);
    h[6] = fmaxf(acc[6] * di + __uint_as_float(w3 << 16) + bb.z, 0.f);
    h[7] = fmaxf(acc[7] * di + __uint_as_float(w3 & 0xFFFF0000u) + bb.w, 0.f);
    unsigned ph[4];
#pragma unroll
    for (int t = 0; t < 4; ++t)
      ph[t] = (unsigned)f2bf(h[2 * t]) | ((unsigned)f2bf(h[2 * t + 1]) << 16);
    *(int4*)(h1 + (size_t)node * DIM + col * 8) =
        make_int4((int)ph[0], (int)ph[1], (int)ph[2], (int)ph[3]);
  }
}

// ---------------- gather2: agg(h1) * dinv -> aggH bf16 (R0 structure, proven) ----------------
__global__ __launch_bounds__(256) void gather_wave_kernel(
    const ushort* __restrict__ featH, const int* __restrict__ csr_src,
    const unsigned* __restrict__ off, const float* __restrict__ dinv,
    ushort* __restrict__ aggH, int N) {
  GATHER_BODY(featH)
  if (eslot == 0) {
    float di = dinv[node];
    unsigned ph[4];
#pragma unroll
    for (int t = 0; t < 4; ++t) {
      ph[t] = (unsigned)f2bf(acc[2 * t] * di) | ((unsigned)f2bf(acc[2 * t + 1] * di) << 16);
    }
    *(int4*)(aggH + (size_t)node * DIM + col * 8) =
        make_int4((int)ph[0], (int)ph[1], (int)ph[2], (int)ph[3]);
  }
}

// ---------------- MFMA SAGE layer (R0's proven kernel, layer 2 + fused lin3) ----------------
__global__ __launch_bounds__(256) void sage_mfma_kernel(
    const ushort* __restrict__ aggH, const ushort* xH,
    const ushort* __restrict__ WlH, const ushort* __restrict__ WrH,
    const float* __restrict__ bias,
    const float* __restrict__ W3l, const float* __restrict__ W3r,
    ushort* __restrict__ outH, float* __restrict__ y, int N) {
  __shared__ ushort As[128 * 64];  // 16 KB
  __shared__ ushort Bs[128 * 64];  // 16 KB

  const int tid = threadIdx.x;
  const int bm = blockIdx.x * 128;
  const int wave = tid >> 6;
  const int lane = tid & 63;
  const int l15 = lane & 15;
  const int quad = lane >> 4;
  const int wm = wave >> 1;
  const int wn = wave & 1;

  f32x4 acc[4][4];
#pragma unroll
  for (int i = 0; i < 4; ++i)
#pragma unroll
    for (int j = 0; j < 4; ++j) acc[i][j] = (f32x4){0.f, 0.f, 0.f, 0.f};

  for (int g = 0; g < 4; ++g) {
    const ushort* Ap = (g < 2) ? aggH : xH;
    const ushort* Wp = (g < 2) ? WlH : WrH;
    const int kt = (g & 1) << 6;
    __syncthreads();
#pragma unroll
    for (int c = 0; c < 4; ++c) {
      int flat = c * 256 + tid;
      int row = flat >> 3;
      int kg = flat & 7;
      int swz = (kg ^ (row & 7)) << 3;
      int grow = bm + row;
      if (grow >= N) grow = N - 1;
      *(int4*)(&As[row * 64 + swz]) = *(const int4*)(Ap + (size_t)grow * DIM + kt + kg * 8);
      *(int4*)(&Bs[row * 64 + swz]) = *(const int4*)(Wp + (size_t)row * DIM + kt + kg * 8);
    }
    __syncthreads();
#pragma unroll
    for (int ks = 0; ks < 2; ++ks) {
      bf16x8 af[4], bfr[4];
      int kg = (ks << 2) + quad;
#pragma unroll
      for (int i = 0; i < 4; ++i) {
        int ar = (wm << 6) + (i << 4) + l15;
        af[i] = *(const bf16x8*)(&As[ar * 64 + ((kg ^ (ar & 7)) << 3)]);
        int br = (wn << 6) + (i << 4) + l15;
        bfr[i] = *(const bf16x8*)(&Bs[br * 64 + ((kg ^ (br & 7)) << 3)]);
      }
#pragma unroll
      for (int i = 0; i < 4; ++i)
#pragma unroll
        for (int j = 0; j < 4; ++j)
          acc[i][j] = __builtin_amdgcn_mfma_f32_16x16x32_bf16(af[i], bfr[j], acc[i][j], 0, 0, 0);
    }
  }

  __syncthreads();  // As/Bs dead; alias epilogue buffers onto As
  float* WcF = reinterpret_cast<float*>(As);        // [128][4] = 2 KB
  float* YpF = reinterpret_cast<float*>(As) + 512;  // [128][4][2] = 4 KB

  if (W3l) {
    for (int t = tid; t < 512; t += 256) {
      int col = t >> 2, c = t & 3;
      WcF[t] = (c < 2) ? W3l[col * 2 + c] : W3r[col * 2 + (c - 2)];
    }
    __syncthreads();
  }

  float bv[4];
#pragma unroll
  for (int j = 0; j < 4; ++j) bv[j] = bias[(wn << 6) + (j << 4) + l15];

#pragma unroll
  for (int i = 0; i < 4; ++i) {
#pragma unroll
    for (int r = 0; r < 4; ++r) {
      const int rowl = (wm << 6) + (i << 4) + (quad << 2) + r;
      const int grow = bm + rowl;
      float p0 = 0.f, p1 = 0.f, p2 = 0.f, p3 = 0.f;
#pragma unroll
      for (int j = 0; j < 4; ++j) {
        int col = (wn << 6) + (j << 4) + l15;
        float v = fmaxf(acc[i][j][r] + bv[j], 0.f);
        ushort h = f2bf(v);
        if (outH && grow < N) outH[(size_t)grow * DIM + col] = h;
        if (W3l) {
          float qv = bf2f(h);
          p0 += qv * WcF[col * 4 + 0];
          p1 += qv * WcF[col * 4 + 1];
          p2 += qv * WcF[col * 4 + 2];
          p3 += qv * WcF[col * 4 + 3];
        }
      }
      if (W3l) {
#pragma unroll
        for (int o = 1; o < 16; o <<= 1) {
          p0 += __shfl_xor(p0, o, 64);
          p1 += __shfl_xor(p1, o, 64);
          p2 += __shfl_xor(p2, o, 64);
          p3 += __shfl_xor(p3, o, 64);
        }
        if (l15 == 0) {
          YpF[(rowl * 4 + 0) * 2 + wn] = p0;
          YpF[(rowl * 4 + 1) * 2 + wn] = p1;
          YpF[(rowl * 4 + 2) * 2 + wn] = p2;
          YpF[(rowl * 4 + 3) * 2 + wn] = p3;
        }
      }
    }
  }

  if (W3l) {
    __syncthreads();
    for (int t = tid; t < 512; t += 256) {
      int grow = bm + (t >> 2);
      if (grow < N) y[(size_t)grow * 4 + (t & 3)] = YpF[t * 2 + 0] + YpF[t * 2 + 1];
    }
  }
}

// ---------------- layer 3: 2-dim CSR gather + bias + relu + log_softmax ----------------
__global__ __launch_bounds__(256) void final3_kernel(const float* __restrict__ y,
                                                     const int* __restrict__ csr_src,
                                                     const unsigned* __restrict__ off,
                                                     const float* __restrict__ dinv,
                                                     const float* __restrict__ b3,
                                                     float* __restrict__ out, int N) {
  int n = blockIdx.x * 256 + threadIdx.x;
  if (n >= N) return;
  unsigned beg = off[n], end = off[n + 1];
  float s0 = 0.f, s1 = 0.f;
  for (unsigned e = beg; e < end; ++e) {
    int s = csr_src[e];
    float2 v = *reinterpret_cast<const float2*>(&y[(size_t)s * 4]);
    s0 += v.x; s1 += v.y;
  }
  float di = dinv[n];
  float o0 = fmaxf(s0 * di + y[(size_t)n * 4 + 2] + b3[0], 0.f);
  float o1 = fmaxf(s1 * di + y[(size_t)n * 4 + 3] + b3[1], 0.f);
  float m = fmaxf(o0, o1);
  float l = m + logf(expf(o0 - m) + expf(o1 - m));
  out[n * 2 + 0] = o0 - l;
  out[n * 2 + 1] = o1 - l;
}

extern "C" void kernel_launch(void* const* d_in, const int* in_sizes, int n_in,
                              void* d_out, int out_size, void* d_ws, size_t ws_size,
                              hipStream_t stream) {
  const float* x   = (const float*)d_in[0];
  const int*   ei  = (const int*)d_in[1];
  const float* W1l = (const float*)d_in[2];
  const float* W1r = (const float*)d_in[3];
  const float* b1  = (const float*)d_in[4];
  const float* W2l = (const float*)d_in[5];
  const float* W2r = (const float*)d_in[6];
  const float* b2  = (const float*)d_in[7];
  const float* W3l = (const float*)d_in[8];
  const float* W3r = (const float*)d_in[9];
  const float* b3  = (const float*)d_in[10];

  const int N = in_sizes[0] / DIM;  // 100000
  const int E = in_sizes[1] / 2;    // 1600000
  const int* src = ei;
  const int* dst = ei + E;
  const int B = (N + 255) / 256;

  char* ws = (char*)d_ws;
  size_t off_b = 0;
  auto alloc = [&](size_t bytes) {
    void* p = ws + off_b;
    off_b = (off_b + bytes + 255) & ~(size_t)255;
    return p;
  };
  unsigned* deg     = (unsigned*)alloc((size_t)N * 4);
  unsigned* excl    = (unsigned*)alloc((size_t)N * 4);
  unsigned* partial = (unsigned*)alloc((size_t)B * 4);
  unsigned* offs    = (unsigned*)alloc((size_t)(N + 1) * 4);
  unsigned* rank    = (unsigned*)alloc((size_t)E * 4);
  int*      csr_src = (int*)alloc((size_t)E * 4);
  float*    dinv    = (float*)alloc((size_t)N * 4);
  ushort*   xl      = (ushort*)alloc((size_t)N * DIM * 2);
  ushort*   xr      = (ushort*)alloc((size_t)N * DIM * 2);
  ushort*   h1      = (ushort*)alloc((size_t)N * DIM * 2);
  ushort*   tabs    = (ushort*)alloc((size_t)2 * 16384 * 2);
  float*    y       = (float*)alloc((size_t)N * 4 * 4);
  // aggH aliases xl: xl is last read by gather1; aggH first written by gather_wave
  // strictly afterwards (proven correct in R4). Workspace stays ~93 MB.
  ushort* aggH = xl;

  const int F  = (E + 255) / 256;   // 6250 edge tiles
  const int G1 = (N + 127) / 128;   // 782 row tiles

  hipMemsetAsync(deg, 0, (size_t)N * 4, stream);
  // K1: pure atomic histogram
  hist_kernel<<<F, 256, 0, stream>>>(dst, deg, rank, E);
  // scan chain
  scan_block_kernel<<<B, 256, 0, stream>>>(deg, excl, partial, dinv, N);
  scan_partials_kernel<<<1, 256, 0, stream>>>(partial, B);
  add_offsets_kernel<<<(N + 256) / 256, 256, 0, stream>>>(excl, partial, offs, N, E);
  // CSR fill: standalone scatter
  csr_fill_kernel<<<F, 256, 0, stream>>>(src, dst, rank, offs, csr_src, E);
  // layer-1 GEMMs (linearity) + W2 wsplit tail blocks
  gemm1_wsplit_kernel<<<2 * G1 + 128, 256, 0, stream>>>(x, W1l, W1r, xl, xr,
                                                        W2l, W2r, tabs, G1, N);

  const ushort* W2lH = tabs;
  const ushort* W2rH = tabs + 16384;
  const int gather_grid = (N + 3) / 4;  // one wave per node

  // layer 1: h1 = relu(mean_agg(xl) + xr + b1)  (fused epilogue, no MFMA kernel)
  gather1_kernel<<<gather_grid, 256, 0, stream>>>(xl, csr_src, offs, dinv, xr, b1, h1, N);
  // layer 2 (R0 structure): agg2 = mean_agg(h1); y = lin3(relu(agg2@W2l + h1@W2r + b2))
  gather_wave_kernel<<<gather_grid, 256, 0, stream>>>(h1, csr_src, offs, dinv, aggH, N);
  sage_mfma_kernel<<<G1, 256, 0, stream>>>(aggH, h1, W2lH, W2rH, b2,
                                           W3l, W3r, nullptr, y, N);
  // layer 3
  final3_kernel<<<(N + 255) / 256, 256, 0, stream>>>(y, csr_src, offs, dinv, b3, (float*)d_out, N);
}